// Round 1
// baseline (1549.936 us; speedup 1.0000x reference)
//
#include <hip/hip_runtime.h>

#define T_DIM 720
#define B_DIM 50000
#define S_DIM 7

#define OFF_SEAS (T_DIM * B_DIM)                     /* 36,000,000 */
#define SEAS_ROWS (S_DIM + 1 + (T_DIM - 1))         /* 727 */
#define OFF_MSLD (OFF_SEAS + SEAS_ROWS * B_DIM)     /* 72,350,000 */
#define N_MSLD (T_DIM - 2)                          /* 718 */

// One step of the recurrence. POS must be a compile-time constant so buf[]
// stays in registers.
#define ESRNN_STEP(POS)                                                        \
  {                                                                            \
    float x = train[t * B_DIM + bc];                                           \
    float s = buf[POS];                                                        \
    float nl = lev_sm * __fdividef(x, s) + oml * lev;                          \
    float ll = __logf(nl);                                                     \
    float ld = ll - llev;                                                      \
    float ns = seas_sm * __fdividef(x, nl) + oms * s;                          \
    buf[POS] = ns;                                                             \
    if (valid) {                                                               \
      levs_out[t * B_DIM + b] = nl;                                            \
      seas_out[(t + 7) * B_DIM + b] = ns;                                      \
    }                                                                          \
    float d = ld - pld;                                                        \
    float sq = (valid && t >= 2) ? d * d : 0.0f;                               \
    _Pragma("unroll")                                                          \
    for (int off = 1; off < 64; off <<= 1) sq += __shfl_xor(sq, off, 64);      \
    if (lane == 0 && t >= 2 && valid) atomicAdd(&acc[t - 2], sq);              \
    pld = ld;                                                                  \
    llev = ll;                                                                 \
    lev = nl;                                                                  \
    ++t;                                                                       \
  }

__global__ __launch_bounds__(256) void esrnn_main(
    const float* __restrict__ train,        // (720, B)
    const float* __restrict__ lev_sms,      // (B,)
    const float* __restrict__ seas_sms,     // (B,)
    const float* __restrict__ init_seas_in, // (B, 7)
    float* __restrict__ levs_out,           // (720, B)
    float* __restrict__ seas_out,           // (727, B)
    float* __restrict__ acc)                // (718,) partial sums
{
  int b = blockIdx.x * blockDim.x + threadIdx.x;
  bool valid = (b < B_DIM);
  int bc = valid ? b : (B_DIM - 1);
  int lane = threadIdx.x & 63;

  float lev_sm = 1.0f / (1.0f + __expf(-lev_sms[bc]));
  float seas_sm = 1.0f / (1.0f + __expf(-seas_sms[bc]));
  float oml = 1.0f - lev_sm;
  float oms = 1.0f - seas_sm;

  float is[7];
#pragma unroll
  for (int j = 0; j < 7; ++j) is[j] = __expf(init_seas_in[bc * 7 + j]);

  float seas0 = is[0];
  float x0 = train[bc];
  float lev = __fdividef(x0, seas0);

  if (valid) {
    levs_out[b] = lev;
#pragma unroll
    for (int j = 0; j < 7; ++j) seas_out[j * B_DIM + b] = is[j];
    seas_out[7 * B_DIM + b] = seas0;
  }

  // buf0 = [init_seas[1:], seas0]
  float buf[7];
#pragma unroll
  for (int j = 0; j < 6; ++j) buf[j] = is[j + 1];
  buf[6] = seas0;

  float llev = __logf(lev);
  float pld = 0.0f;

  int t = 1;
  // 719 steps: 102 full groups of 7 (t=1..714; pos=(t-1)%7 == u), then 5 more
  for (int g = 0; g < 102; ++g) {
    ESRNN_STEP(0)
    ESRNN_STEP(1)
    ESRNN_STEP(2)
    ESRNN_STEP(3)
    ESRNN_STEP(4)
    ESRNN_STEP(5)
    ESRNN_STEP(6)
  }
  // t = 715..719, (t-1)%7 = 0..4
  ESRNN_STEP(0)
  ESRNN_STEP(1)
  ESRNN_STEP(2)
  ESRNN_STEP(3)
  ESRNN_STEP(4)
}

__global__ void esrnn_finish(const float* __restrict__ acc,
                             float* __restrict__ msld) {
  int i = blockIdx.x * blockDim.x + threadIdx.x;
  if (i < N_MSLD) msld[i] = acc[i] * (1.0f / (float)B_DIM);
}

extern "C" void kernel_launch(void* const* d_in, const int* in_sizes, int n_in,
                              void* d_out, int out_size, void* d_ws,
                              size_t ws_size, hipStream_t stream) {
  const float* train = (const float*)d_in[0];
  const float* lev_sms = (const float*)d_in[1];
  const float* seas_sms = (const float*)d_in[2];
  const float* init_seas = (const float*)d_in[3];

  float* out = (float*)d_out;
  float* levs = out;
  float* seas = out + OFF_SEAS;
  float* msld = out + OFF_MSLD;
  float* acc = (float*)d_ws;

  hipMemsetAsync(d_ws, 0, N_MSLD * sizeof(float), stream);

  dim3 grid((B_DIM + 255) / 256);
  esrnn_main<<<grid, 256, 0, stream>>>(train, lev_sms, seas_sms, init_seas,
                                       levs, seas, acc);
  esrnn_finish<<<(N_MSLD + 255) / 256, 256, 0, stream>>>(acc, msld);
}

// Round 2
// 296.773 us; speedup vs baseline: 5.2226x; 5.2226x over previous
//
#include <hip/hip_runtime.h>

#define T_DIM 720
#define B_DIM 50000
#define S_DIM 7

#define OFF_SEAS (T_DIM * B_DIM)                  /* 36,000,000 */
#define SEAS_ROWS (S_DIM + 1 + (T_DIM - 1))       /* 727 */
#define OFF_MSLD (OFF_SEAS + SEAS_ROWS * B_DIM)   /* 72,350,000 */
#define N_MSLD (T_DIM - 2)                        /* 718 */

#define NBLK 196
#define NW (NBLK * 4)                             /* 784 waves total */

// One recurrence step. POS is compile-time constant -> buf/xq/sqv stay in regs.
#define ESRNN_STEP(POS)                                                        \
  {                                                                            \
    float x = xq[POS];                                                         \
    float s = buf[POS];                                                        \
    float nl = fmaf(lev_sm, __fdividef(x, s), oml * lev);                      \
    float ll = __logf(nl);                                                     \
    float ld = ll - llev;                                                      \
    float ns = fmaf(seas_sm, __fdividef(x, nl), oms * s);                      \
    buf[POS] = ns;                                                             \
    if (valid) {                                                               \
      levs_out[t * B_DIM + b] = nl;                                            \
      seas_out[(t + 7) * B_DIM + b] = ns;                                      \
    }                                                                          \
    float d = ld - pld;                                                        \
    sqv[POS] = (valid && t >= 2) ? d * d : 0.0f;                               \
    pld = ld;                                                                  \
    llev = ll;                                                                 \
    lev = nl;                                                                  \
    ++t;                                                                       \
  }

// Reduce sqv[J] across the wave, store per-wave partial (no atomics).
#define ESRNN_REDUCE(J)                                                        \
  {                                                                            \
    float v = sqv[J];                                                          \
    _Pragma("unroll")                                                          \
    for (int off = 1; off < 64; off <<= 1) v += __shfl_xor(v, off, 64);        \
    int row = tb + (J)-2;                                                      \
    if (lane == 0 && row >= 0) partial[row * NW + wid] = v;                    \
  }

__global__ __launch_bounds__(256) void esrnn_main(
    const float* __restrict__ train,        // (720, B)
    const float* __restrict__ lev_sms,      // (B,)
    const float* __restrict__ seas_sms,     // (B,)
    const float* __restrict__ init_seas_in, // (B, 7)
    float* __restrict__ levs_out,           // (720, B)
    float* __restrict__ seas_out,           // (727, B)
    float* __restrict__ partial)            // (718, NW) per-wave partials
{
  int b = blockIdx.x * blockDim.x + threadIdx.x;
  bool valid = (b < B_DIM);
  int bc = valid ? b : (B_DIM - 1);
  int lane = threadIdx.x & 63;
  int wid = (blockIdx.x * 256 + threadIdx.x) >> 6;  // 0..783

  float lev_sm = 1.0f / (1.0f + __expf(-lev_sms[bc]));
  float seas_sm = 1.0f / (1.0f + __expf(-seas_sms[bc]));
  float oml = 1.0f - lev_sm;
  float oms = 1.0f - seas_sm;

  float is[7];
#pragma unroll
  for (int j = 0; j < 7; ++j) is[j] = __expf(init_seas_in[bc * 7 + j]);

  float seas0 = is[0];
  float x0 = train[bc];
  float lev = __fdividef(x0, seas0);

  if (valid) {
    levs_out[b] = lev;
#pragma unroll
    for (int j = 0; j < 7; ++j) seas_out[j * B_DIM + b] = is[j];
    seas_out[7 * B_DIM + b] = seas0;
  }

  float buf[7];
#pragma unroll
  for (int j = 0; j < 6; ++j) buf[j] = is[j + 1];
  buf[6] = seas0;

  float llev = __logf(lev);
  float pld = 0.0f;

  // ---- software-pipelined x loads, 2 groups (14 rows) ahead ----
  float xq[7], xn1[7], xn2[7], sqv[7];
#pragma unroll
  for (int j = 0; j < 7; ++j) xq[j] = train[(1 + j) * B_DIM + bc];
#pragma unroll
  for (int j = 0; j < 7; ++j) xn1[j] = train[(8 + j) * B_DIM + bc];

  int t = 1;
  for (int g = 0; g < 102; ++g) {
    // prefetch group g+2 (clamp row to 719; extra loads harmless)
    int tp = 1 + 7 * (g + 2);
#pragma unroll
    for (int j = 0; j < 7; ++j) {
      int r = tp + j;
      xn2[j] = train[(r > 719 ? 719 : r) * B_DIM + bc];
    }

    int tb = t;  // first t of this group
    ESRNN_STEP(0)
    ESRNN_STEP(1)
    ESRNN_STEP(2)
    ESRNN_STEP(3)
    ESRNN_STEP(4)
    ESRNN_STEP(5)
    ESRNN_STEP(6)

    ESRNN_REDUCE(0)
    ESRNN_REDUCE(1)
    ESRNN_REDUCE(2)
    ESRNN_REDUCE(3)
    ESRNN_REDUCE(4)
    ESRNN_REDUCE(5)
    ESRNN_REDUCE(6)

#pragma unroll
    for (int j = 0; j < 7; ++j) {
      xq[j] = xn1[j];
      xn1[j] = xn2[j];
    }
  }

  // tail: t = 715..719, buf pos 0..4
  {
    int tb = t;
    ESRNN_STEP(0)
    ESRNN_STEP(1)
    ESRNN_STEP(2)
    ESRNN_STEP(3)
    ESRNN_STEP(4)
    ESRNN_REDUCE(0)
    ESRNN_REDUCE(1)
    ESRNN_REDUCE(2)
    ESRNN_REDUCE(3)
    ESRNN_REDUCE(4)
  }
}

__global__ __launch_bounds__(64) void esrnn_reduce2(
    const float* __restrict__ partial, float* __restrict__ msld) {
  int row = blockIdx.x;  // 0..717
  int lane = threadIdx.x;
  float s = 0.0f;
  for (int i = lane; i < NW; i += 64) s += partial[row * NW + i];
#pragma unroll
  for (int off = 1; off < 64; off <<= 1) s += __shfl_xor(s, off, 64);
  if (lane == 0) msld[row] = s * (1.0f / (float)B_DIM);
}

extern "C" void kernel_launch(void* const* d_in, const int* in_sizes, int n_in,
                              void* d_out, int out_size, void* d_ws,
                              size_t ws_size, hipStream_t stream) {
  const float* train = (const float*)d_in[0];
  const float* lev_sms = (const float*)d_in[1];
  const float* seas_sms = (const float*)d_in[2];
  const float* init_seas = (const float*)d_in[3];

  float* out = (float*)d_out;
  float* levs = out;
  float* seas = out + OFF_SEAS;
  float* msld = out + OFF_MSLD;
  float* partial = (float*)d_ws;  // 718*784*4 = 2.25 MB

  esrnn_main<<<NBLK, 256, 0, stream>>>(train, lev_sms, seas_sms, init_seas,
                                       levs, seas, partial);
  esrnn_reduce2<<<N_MSLD, 64, 0, stream>>>(partial, msld);
}